// Round 9
// baseline (292.340 us; speedup 1.0000x reference)
//
#include <hip/hip_runtime.h>
#include <math.h>

typedef unsigned short ushortT;
typedef unsigned int uintT;
typedef __attribute__((ext_vector_type(8))) short short8;
typedef __attribute__((ext_vector_type(16))) float f32x16;
#define MFMA32(a, b, c) __builtin_amdgcn_mfma_f32_32x32x16_bf16((a), (b), (c), 0, 0, 0)

// MFMA 32x32x16 layouts (gfx950, HW-verified m74/m101/m120):
//  A-frag: lane reads A[m = lane&31][k = (lane>>5)*8 + j], j=0..7
//  B-frag: lane reads B[k = (lane>>5)*8 + j][n = lane&31]
//  C/D:    col = lane&31, row = (reg&3) + 8*(reg>>2) + 4*(lane>>5)

#define LOG2E 1.4426950408889634f

static __device__ __forceinline__ ushortT f2b(float f) {
    union { float f; uintT u; } v; v.f = f;
    uintT u = v.u;
    u += 0x7fffu + ((u >> 16) & 1u);     // round-to-nearest-even
    return (ushortT)(u >> 16);
}
static __device__ __forceinline__ uintT pack2(float a, float b) {
    return (uintT)f2b(a) | ((uintT)f2b(b) << 16);
}
// truncating bf16 pack of two fp32 in ONE v_perm_b32 (low16=a, high16=b)
static __device__ __forceinline__ uintT pack2t(float a, float b) {
    union { float f; uintT u; } x0, x1; x0.f = a; x1.f = b;
    return __builtin_amdgcn_perm(x1.u, x0.u, 0x07060302u);
}
static __device__ __forceinline__ float blo(uintT u) {
    union { uintT u; float f; } v; v.u = u << 16; return v.f;
}
static __device__ __forceinline__ float bhi(uintT u) {
    union { uintT u; float f; } v; v.u = u & 0xffff0000u; return v.f;
}
static __device__ __forceinline__ f32x16 zero16() {
    f32x16 z;
    #pragma unroll
    for (int i = 0; i < 16; ++i) z[i] = 0.f;
    return z;
}

#define B_N 2
#define H_N 8
#define L_N 2048
#define NQB 16
#define NKB 32

// ---------------------------------------------------------------------------
// Fused prep: x fp32->bf16 (blocks 0..2047; block 0 also zeroes the split-K
// counters), Wqkv transpose (2048..2815), Wproj transpose (2816..3071).
// ---------------------------------------------------------------------------
__global__ __launch_bounds__(256) void prep_kernel(
    const float* __restrict__ x, ushortT* __restrict__ xb,
    const float* __restrict__ Wq, ushortT* __restrict__ Wqt,
    const float* __restrict__ Wp, ushortT* __restrict__ Wpt,
    int* __restrict__ cnt) {
    const int bid = blockIdx.x, t = threadIdx.x;
    __shared__ float tile[32][33];
    if (bid < 2048) {
        if (bid == 0) cnt[t] = 0;     // 256 split-K counters (re-zeroed every call)
        int i = (bid * 256 + t) * 4;
        float4 v = *(const float4*)(x + i);
        uint2 o; o.x = pack2(v.x, v.y); o.y = pack2(v.z, v.w);
        *(uint2*)(xb + i) = o;
        return;
    }
    const float* W; ushortT* Wt; int C, c0, r0;
    if (bid < 2816) {
        const int b = bid - 2048;
        W = Wq; Wt = Wqt; C = 1536;
        c0 = (b % 48) * 32; r0 = (b / 48) * 32;
    } else {
        const int b = bid - 2816;
        W = Wp; Wt = Wpt; C = 512;
        c0 = (b & 15) * 32; r0 = (b >> 4) * 32;
    }
    const int tx = t & 31, ty = t >> 5;
    #pragma unroll
    for (int i = 0; i < 4; ++i)
        tile[ty + 8 * i][tx] = W[(size_t)(r0 + ty + 8 * i) * C + c0 + tx];
    __syncthreads();
    #pragma unroll
    for (int i = 0; i < 4; ++i) {
        int rr = ty + 8 * i;
        Wt[(size_t)(c0 + rr) * 512 + r0 + tx] = f2b(tile[tx][rr]);
    }
}

// ---------------------------------------------------------------------------
// QKV GEMM (bf16 MFMA): 128x64 tiles, grid (24,32) = 768 blocks = 3/CU.
// Wave w owns rows [32w,32w+32), 2 col-tiles of 32. Double-buffered LDS.
//  -> qb (scaled 0.125*LOG2E), kbuf [bh][L][64], vt [bh][kb][d][64key]
//  fp32 block means qm (scaled 0.125), km.
// ---------------------------------------------------------------------------
__global__ __launch_bounds__(256) void qkv_gemm_kernel(
    const ushortT* __restrict__ xb, const ushortT* __restrict__ wt,
    const float* __restrict__ bias,
    ushortT* __restrict__ qb, ushortT* __restrict__ kbuf, ushortT* __restrict__ vt,
    float* __restrict__ qm, float* __restrict__ km) {
    __shared__ __align__(16) ushortT As[2][128 * 40];
    __shared__ __align__(16) ushortT Bs[2][64 * 40];
    __shared__ float sumbuf[4][64];
    const int t = threadIdx.x;
    const int l = t & 63, w = t >> 6;
    const int lm = l & 31, lh = l >> 5;
    const int rowbase = blockIdx.y * 128;
    const int colbase = blockIdx.x * 64;

    f32x16 acc[2];
    acc[0] = zero16(); acc[1] = zero16();

    // A loader: thread -> row t>>1 (0..127), k-half t&1 (16 elems)
    const int r = t >> 1, half = t & 1;
    const ushortT* Ag = xb + (size_t)(rowbase + r) * 512 + half * 16;
    const int soA = r * 40 + half * 16;
    // B loader: thread -> row t>>2 (0..63), k-quarter t&3 (8 elems)
    const int rb = t >> 2, q4 = t & 3;
    const ushortT* Bg = wt + (size_t)(colbase + rb) * 512 + q4 * 8;
    const int soB = rb * 40 + q4 * 8;

    uint4 a0, a1, b0;
    a0 = *(const uint4*)(Ag); a1 = *(const uint4*)(Ag + 8);
    b0 = *(const uint4*)(Bg);
    *(uint4*)(&As[0][soA]) = a0; *(uint4*)(&As[0][soA] + 8) = a1;
    *(uint4*)(&Bs[0][soB]) = b0;

    for (int k0 = 0; k0 < 512; k0 += 32) {
        const int cur = (k0 >> 5) & 1;
        __syncthreads();
        if (k0 < 480) {
            a0 = *(const uint4*)(Ag + k0 + 32); a1 = *(const uint4*)(Ag + k0 + 40);
            b0 = *(const uint4*)(Bg + k0 + 32);
        }
        #pragma unroll
        for (int ks = 0; ks < 2; ++ks) {
            const int ko = 16 * ks + 8 * lh;
            short8 af  = *(const short8*)(&As[cur][(32 * w + lm) * 40 + ko]);
            short8 b_0 = *(const short8*)(&Bs[cur][lm * 40 + ko]);
            short8 b_1 = *(const short8*)(&Bs[cur][(32 + lm) * 40 + ko]);
            acc[0] = MFMA32(af, b_0, acc[0]);
            acc[1] = MFMA32(af, b_1, acc[1]);
        }
        if (k0 < 480) {
            const int nxt = cur ^ 1;
            *(uint4*)(&As[nxt][soA]) = a0; *(uint4*)(&As[nxt][soA] + 8) = a1;
            *(uint4*)(&Bs[nxt][soB]) = b0;
        }
    }

    // epilogue: 64-col tile = exactly one (which, head)
    const int which = blockIdx.x >> 3;            // 0=q 1=k 2=v
    const int h = blockIdx.x & 7;
    const int by = blockIdx.y;
    const int b = by >> 4;
    const size_t hb = (size_t)(b * 8 + h);
    float bias2[2];
    #pragma unroll
    for (int nt = 0; nt < 2; ++nt) bias2[nt] = bias[colbase + 32 * nt + lm];
    float msum[2] = {0.f, 0.f};
    #pragma unroll
    for (int nt = 0; nt < 2; ++nt) {
        const int dd = 32 * nt + lm;
        #pragma unroll
        for (int rg = 0; rg < 16; ++rg) {
            const int row_local = 32 * w + (rg & 3) + 8 * (rg >> 2) + 4 * lh;
            const int ll = (rowbase + row_local) & 2047;
            float val = acc[nt][rg] + bias2[nt];
            if (which == 0) {
                val *= 0.125f;
                msum[nt] += val;
                qb[(hb * 2048 + ll) * 64 + dd] = f2b(val * LOG2E);
            } else if (which == 1) {
                msum[nt] += val;
                kbuf[(hb * 2048 + ll) * 64 + dd] = f2b(val);
            } else {
                vt[hb * 131072 + (size_t)(ll >> 6) * 4096 + dd * 64 + (ll & 63)] = f2b(val);
            }
        }
    }
    if (which == 2) return;
    #pragma unroll
    for (int nt = 0; nt < 2; ++nt) {
        float s = msum[nt] + __shfl_xor(msum[nt], 32);   // full 32-row col sum
        if (l < 32) sumbuf[w][32 * nt + lm] = s;
    }
    __syncthreads();
    if (which == 0) {
        if (t < 64) {
            const int qbi = by & 15;
            qm[(hb * 16 + qbi) * 64 + t] =
                (sumbuf[0][t] + sumbuf[1][t] + sumbuf[2][t] + sumbuf[3][t]) * (1.0f / 128.0f);
        }
    } else {
        if (t < 128) {
            const int d = t & 63, pair = t >> 6;      // pair 0: waves 0-1, 1: waves 2-3
            const int kbi = 2 * (by & 15) + pair;
            km[(hb * 32 + kbi) * 64 + d] =
                (sumbuf[2 * pair][d] + sumbuf[2 * pair + 1][d]) * (1.0f / 64.0f);
        }
    }
}

// ---------------------------------------------------------------------------
// Fused cos + mask: one block per bh (512 threads). Token min-cosines (qs/ks
// stay in LDS), pooled softmax, sort-free rank-sum CDF keep, fallbacks.
// qb carries a uniform positive scale (0.125*log2e) - cosine scale-invariant.
// ---------------------------------------------------------------------------
__global__ __launch_bounds__(512) void cosmask_kernel(
    const ushortT* __restrict__ qb, const ushortT* __restrict__ kbuf,
    const float* __restrict__ qm, const float* __restrict__ km,
    int* __restrict__ maskp) {
    const int bh = blockIdx.x, t = threadIdx.x;
    __shared__ float qmS[1024];
    __shared__ float kmS[2048];
    __shared__ float nrm[48];        // qn[0..15], kn[16..47]
    __shared__ float pooled[512];
    __shared__ float pnorm[512];
    __shared__ float tokcos[2048];
    __shared__ float qsS[16], ksS[32];
    for (int i = t; i < 1024; i += 512) qmS[i] = qm[(size_t)bh * 1024 + i];
    for (int i = t; i < 2048; i += 512) kmS[i] = km[(size_t)bh * 2048 + i];
    __syncthreads();
    if (t < 16) {
        float s = 0.f;
        #pragma unroll
        for (int d = 0; d < 64; ++d) s += qmS[t * 64 + d] * qmS[t * 64 + d];
        nrm[t] = sqrtf(s);
    } else if (t < 48) {
        const int kb = t - 16;
        float s = 0.f;
        #pragma unroll
        for (int d = 0; d < 64; ++d) s += kmS[kb * 64 + d] * kmS[kb * 64 + d];
        nrm[16 + kb] = sqrtf(s);
    }
    {   // pooled logits (qm pre-scaled by 0.125 -> dot is the scaled logit)
        const int qbi = t >> 5, kbi = t & 31;
        float dot = 0.f;
        #pragma unroll
        for (int d = 0; d < 64; ++d) dot += qmS[qbi * 64 + d] * kmS[kbi * 64 + d];
        pooled[t] = dot;
    }
    __syncthreads();
    // q token cosines: 4 tokens per thread
    for (int tok = t; tok < 2048; tok += 512) {
        const int qbk = tok >> 7;
        const ushortT* row = qb + ((size_t)bh * 2048 + tok) * 64;
        const float* m = &qmS[qbk * 64];
        float dot = 0.f, nn = 0.f;
        #pragma unroll
        for (int c = 0; c < 8; ++c) {
            uint4 u = *(const uint4*)(row + c * 8);
            float f0 = blo(u.x), f1 = bhi(u.x), f2 = blo(u.y), f3 = bhi(u.y);
            float f4 = blo(u.z), f5 = bhi(u.z), f6 = blo(u.w), f7 = bhi(u.w);
            const int db = c * 8;
            dot += f0 * m[db] + f1 * m[db + 1] + f2 * m[db + 2] + f3 * m[db + 3]
                 + f4 * m[db + 4] + f5 * m[db + 5] + f6 * m[db + 6] + f7 * m[db + 7];
            nn += f0 * f0 + f1 * f1 + f2 * f2 + f3 * f3 + f4 * f4 + f5 * f5 + f6 * f6 + f7 * f7;
        }
        tokcos[tok] = dot / ((sqrtf(nn) + 1e-6f) * (nrm[qbk] + 1e-6f));
    }
    __syncthreads();
    if (t < 16) {
        float mn = 1e30f;
        for (int i = 0; i < 128; ++i) mn = fminf(mn, tokcos[t * 128 + i]);
        qsS[t] = mn;
    }
    __syncthreads();   // before tokcos reuse
    // k token cosines
    for (int tok = t; tok < 2048; tok += 512) {
        const int kbk = tok >> 6;
        const ushortT* row = kbuf + ((size_t)bh * 2048 + tok) * 64;
        const float* m = &kmS[kbk * 64];
        float dot = 0.f, nn = 0.f;
        #pragma unroll
        for (int c = 0; c < 8; ++c) {
            uint4 u = *(const uint4*)(row + c * 8);
            float f0 = blo(u.x), f1 = bhi(u.x), f2 = blo(u.y), f3 = bhi(u.y);
            float f4 = blo(u.z), f5 = bhi(u.z), f6 = blo(u.w), f7 = bhi(u.w);
            const int db = c * 8;
            dot += f0 * m[db] + f1 * m[db + 1] + f2 * m[db + 2] + f3 * m[db + 3]
                 + f4 * m[db + 4] + f5 * m[db + 5] + f6 * m[db + 6] + f7 * m[db + 7];
            nn += f0 * f0 + f1 * f1 + f2 * f2 + f3 * f3 + f4 * f4 + f5 * f5 + f6 * f6 + f7 * f7;
        }
        tokcos[tok] = dot / ((sqrtf(nn) + 1e-6f) * (nrm[16 + kbk] + 1e-6f));
    }
    __syncthreads();
    if (t < 32) {
        float mn = 1e30f;
        for (int i = 0; i < 64; ++i) mn = fminf(mn, tokcos[t * 64 + i]);
        ksS[t] = mn;
    } else if (t >= 64 && t < 80) {      // per-row softmax normalize
        const int row = t - 64;
        float mx = -1e30f;
        #pragma unroll
        for (int kb = 0; kb < NKB; ++kb) mx = fmaxf(mx, pooled[row * 32 + kb]);
        float sum = 0.f;
        #pragma unroll
        for (int kb = 0; kb < NKB; ++kb) {
            const float e = expf(pooled[row * 32 + kb] - mx);
            pnorm[row * 32 + kb] = e;
            sum += e;
        }
        const float inv = 1.0f / sum;
        #pragma unroll
        for (int kb = 0; kb < NKB; ++kb) pnorm[row * 32 + kb] *= inv;
    }
    __syncthreads();
    {   // rank-sum CDF keep + fallbacks
        const int row = t >> 5, kb = t & 31;
        const float pk = pnorm[row * 32 + kb];
        float before = 0.f;
        #pragma unroll
        for (int j = 0; j < NKB; ++j) {
            const float pj = pnorm[row * 32 + j];
            if (pj > pk || (pj == pk && j < kb)) before += pj;
        }
        const bool keep = before < 0.98f;
        const bool qfb = !(qsS[row] > 0.6f);
        const bool kfb = !(ksS[kb] > 0.6f);
        maskp[((size_t)bh * 16 + row) * 32 + kb] = (keep || qfb || kfb) ? 1 : 0;
    }
}

// ---------------------------------------------------------------------------
// Flash attention, bf16 MFMA, S^T form, exp2 softmax (scale folded into qb,
// shift cancels in O/l), K-split NC = gridDim.z, LDS double-buffered K/V,
// register P-exchange. FUSED split-K reduction: last block per (qt,bh)
// (device-scope atomic counter + threadfence) combines all chunks' partials
// and writes final ob - no separate reduce launch.
// ---------------------------------------------------------------------------
__global__ __launch_bounds__(256) void attn_kernel(
    const ushortT* __restrict__ qb, const ushortT* __restrict__ kbuf,
    const ushortT* __restrict__ vt, const int* __restrict__ maskp,
    uintT* __restrict__ pc0, uintT* __restrict__ pc1,
    uintT* __restrict__ pc2, uintT* __restrict__ pc3,
    float* __restrict__ lp, int* cnt, ushortT* ob) {
    __shared__ __align__(16) ushortT Ks[2][64 * 72];
    __shared__ __align__(16) ushortT Vs[2][64 * 72];
    __shared__ int klist[33];
    __shared__ int lastf;
    const int t = threadIdx.x;
    const int l = t & 63, w = t >> 6;
    const int lm = l & 31, lh = l >> 5;
    const int qt = blockIdx.x, bh = blockIdx.y, kc = blockIdx.z;
    const int NC = gridDim.z;

    // kept-block list via ballot (wave 0)
    if (w == 0) {
        const int* mrow = maskp + ((size_t)bh * 16 + qt) * 32;
        const int keep = (l < 32) ? mrow[l] : 0;
        unsigned long long bal = __ballot(keep != 0);
        if (keep) {
            const int rank = __popcll(bal & ((1ULL << l) - 1ULL));
            klist[rank] = l;
        }
        if (l == 0) klist[32] = __popcll(bal);
    }
    // Q B-frags straight from global
    const ushortT* qg = qb + ((size_t)bh * 2048 + qt * 128) * 64;
    short8 qf[4];
    #pragma unroll
    for (int ksd = 0; ksd < 4; ++ksd)
        qf[ksd] = *(const short8*)(qg + (32 * w + lm) * 64 + 16 * ksd + 8 * lh);
    __syncthreads();   // klist visible

    const int cnt_k = klist[32];
    const int per = cnt_k / NC, rem = cnt_k - per * NC;
    const int n = per + (kc < rem ? 1 : 0);
    const int s = kc * per + (kc < rem ? kc : rem);

    const ushortT* kgb = kbuf + (size_t)bh * 131072;
    const ushortT* vgb = vt + (size_t)bh * 131072;
    const int cr = t >> 3, cp = (t & 7) * 8;
    const int gK0 = cr * 64 + cp, gK1 = gK0 + 2048;
    const int sK0 = cr * 72 + cp, sK1 = sK0 + 2304;

    f32x16 oacc[2];
    oacc[0] = zero16(); oacc[1] = zero16();
    float l_i = 0.f;

    uint4 ka0, ka1, va0, va1;
    if (n > 0) {
        const int kb0 = klist[s];
        const ushortT* kg = kgb + (size_t)kb0 * 4096;
        const ushortT* vg = vgb + (size_t)kb0 * 4096;
        ka0 = *(const uint4*)(kg + gK0); ka1 = *(const uint4*)(kg + gK1);
        va0 = *(const uint4*)(vg + gK0); va1 = *(const uint4*)(vg + gK1);
        *(uint4*)(&Ks[0][sK0]) = ka0; *(uint4*)(&Ks[0][sK1]) = ka1;
        *(uint4*)(&Vs[0][sK0]) = va0; *(uint4*)(&Vs[0][sK1]) = va1;
    }

    for (int i = 0; i < n; ++i) {
        const int cur = i & 1;
        __syncthreads();
        if (i + 1 < n) {
            const int kbn = klist[s + i + 1];
            const ushortT* kg = kgb + (size_t)kbn * 4096;
            const ushortT* vg = vgb + (size_t)kbn * 4096;
            ka0 = *(const uint4*)(kg + gK0); ka1 = *(const uint4*)(kg + gK1);
            va0 = *(const uint4*)(vg + gK0); va1 = *(const uint4*)(vg + gK1);
        }
        // S^T = K * Q^T  (S already in log2e units)
        f32x16 sacc[2];
        sacc[0] = zero16(); sacc[1] = zero16();
        #pragma unroll
        for (int ksd = 0; ksd < 4; ++ksd) {
            const int ko = 16 * ksd + 8 * lh;
            short8 kf0 = *(const short8*)(&Ks[cur][lm * 72 + ko]);
            short8 kf1 = *(const short8*)(&Ks[cur][(32 + lm) * 72 + ko]);
            sacc[0] = MFMA32(kf0, qf[ksd], sacc[0]);
            sacc[1] = MFMA32(kf1, qf[ksd], sacc[1]);
        }
        // p = exp2(s): no shift (global constant cancels in O/l)
        float psum0 = 0.f, psum1 = 0.f;
        uintT uu[2][4][2];   // [mt][rg-block][pair]
        #pragma unroll
        for (int mt = 0; mt < 2; ++mt) {
            #pragma unroll
            for (int rp = 0; rp < 8; ++rp) {
                const float e0 = exp2f(sacc[mt][2 * rp]);
                const float e1 = exp2f(sacc[mt][2 * rp + 1]);
                psum0 += e0; psum1 += e1;
                uu[mt][rp >> 1][rp & 1] = pack2t(e0, e1);
            }
        }
        float psum = psum0 + psum1;
        psum += __shfl_xor(psum, 32);
        l_i += psum;
        // O^T += V^T * P^T ; P^T B-frag via lane pair-exchange
        #pragma unroll
        for (int ksk = 0; ksk < 4; ++ksk) {
            const int mt = ksk >> 1, par = ksk & 1;
            const uintT kA = lh ? uu[mt][2 * par + 1][0] : uu[mt][2 * par][0];
            const uintT kB = lh ? uu[mt][2 * par + 1][1] : uu[mt][2 * par][1];
            const uintT sA = lh ? uu[mt][2 * par][0] : uu[mt][2 * par + 1][0];
            const uintT sB = lh ? uu[mt][2 * par][1] : uu[mt][2 * par + 1][1];
            const uintT rA = (uintT)__shfl_xor((int)sA, 32);
            const uintT rB = (uintT)__shfl_xor((int)sB, 32);
            union { uintT u[4]; short8 v; } cv;
            if (lh == 0) { cv.u[0] = kA; cv.u[1] = kB; cv.u[2] = rA; cv.u[3] = rB; }
            else         { cv.u[0] = rA; cv.u[1] = rB; cv.u[2] = kA; cv.u[3] = kB; }
            const int ko = 16 * ksk + 8 * lh;
            short8 vf0 = *(const short8*)(&Vs[cur][lm * 72 + ko]);
            short8 vf1 = *(const short8*)(&Vs[cur][(32 + lm) * 72 + ko]);
            oacc[0] = MFMA32(vf0, cv.v, oacc[0]);
            oacc[1] = MFMA32(vf1, cv.v, oacc[1]);
        }
        if (i + 1 < n) {
            const int nxt = cur ^ 1;
            *(uint4*)(&Ks[nxt][sK0]) = ka0; *(uint4*)(&Ks[nxt][sK1]) = ka1;
            *(uint4*)(&Vs[nxt][sK0]) = va0; *(uint4*)(&Vs[nxt][sK1]) = va1;
        }
    }
    // partial l + partial O^T (bf16, C-layout, coalesced)
    if (lh == 0)
        lp[kc * 32768 + ((size_t)bh * 16 + qt) * 128 + 32 * w + lm] = l_i;
    uintT pu[16];
    #pragma unroll
    for (int mt = 0; mt < 2; ++mt)
        #pragma unroll
        for (int rp = 0; rp < 8; ++rp)
            pu[mt * 8 + rp] = pack2(oacc[mt][2 * rp], oacc[mt][2 * rp + 1]);
    uintT* pcb = (kc == 0) ? pc0 : (kc == 1) ? pc1 : (kc == 2) ? pc2 : pc3;
    const size_t base = (((size_t)bh * 16 + qt) * 4 + w) * 1024 + l * 4;
    #pragma unroll
    for (int i4 = 0; i4 < 4; ++i4)
        *(uint4*)(pcb + base + i4 * 256) =
            make_uint4(pu[i4 * 4], pu[i4 * 4 + 1], pu[i4 * 4 + 2], pu[i4 * 4 + 3]);

    // ---- fused split-K reduction: last finishing block combines chunks ----
    __threadfence();                      // release: partials visible device-wide
    if (t == 0) {
        const int prev = atomicAdd(cnt + (bh * 16 + qt), 1);
        lastf = (prev == NC - 1) ? 1 : 0;
    }
    __syncthreads();
    if (!lastf) return;
    __threadfence();                      // acquire: other chunks' partials
    float accL[16], accH[16];
    #pragma unroll
    for (int i = 0; i < 16; ++i) { accL[i] = 0.f; accH[i] = 0.f; }
    const int qrow = 32 * w + lm;
    float lsum = 0.f;
    #pragma unroll
    for (int c = 0; c < 4; ++c) {
        if (c >= NC) break;
        const uintT* p = (c == 0) ? pc0 : (c == 1) ? pc1 : (c == 2) ? pc2 : pc3;
        #pragma unroll
        for (int i4 = 0; i4 < 4; ++i4) {
            uint4 v = *(const uint4*)(p + base + i4 * 256);
            accL[i4 * 4 + 0] += blo(v.x); accH[i4 * 4 + 0] += bhi(v.x);
            accL[i4 * 4 + 1] += blo(v.y); accH[i4 * 4 + 1] += bhi(v.y);
            accL[i4 * 4 + 2] += blo(v.z); accH[i4 * 4 + 2] += bhi(v.z);
            accL[i4 * 4 + 3] += blo(v.w); accH[i4 * 4 + 3] += bhi(v.w);
        }
        lsum += lp[c * 32768 + ((size_t)bh * 16 + qt) * 128 + qrow];
    }
    const float invl = 1.0f / lsum;
    ushortT* orow = ob + ((size_t)bh * 2048 + qt * 128 + qrow) * 64;
    #pragma unroll
    for (int idx = 0; idx < 16; ++idx) {
        const int mt = idx >> 3, rp = idx & 7;
        const int d0 = 32 * mt + 8 * (rp >> 1) + 4 * lh + 2 * (rp & 1);
        *(uintT*)(orow + d0) = pack2(accL[idx] * invl, accH[idx] * invl);
    }
}

// ---------------------------------------------------------------------------
// Proj GEMM: 64x64 tiles, grid (8,64) = 512 blocks = 2 waves/SIMD.
// ob (gathered [4096,512] bf16) @ Wprojt^T + bias -> out fp32.
// ---------------------------------------------------------------------------
__global__ __launch_bounds__(256) void proj_gemm_kernel(
    const ushortT* __restrict__ ob, const ushortT* __restrict__ wpt,
    const float* __restrict__ bias, float* __restrict__ out) {
    __shared__ __align__(16) ushortT As[2][64 * 40];
    __shared__ __align__(16) ushortT Bs[2][64 * 40];
    const int t = threadIdx.x;
    const int l = t & 63, w = t >> 6;
    const int lm = l & 31, lh = l >> 5;
    const int rh = w & 1, ch = w >> 1;            // wave -> 32-row half, 32-col half
    const int rowbase = blockIdx.y * 64;
    const int colbase = blockIdx.x * 64;

    f32x16 acc = zero16();

    const int r = t >> 2, q4 = t & 3;             // row 0..63, k-quarter (8 elems)
    const int token = rowbase + r;
    const int b2 = token >> 11, lt = token & 2047;
    const int so = r * 40 + q4 * 8;
    const ushortT* obbase = ob + ((size_t)(b2 * 8) * 2048 + lt) * 64 + q4 * 8;
    const ushortT* Bg = wpt + (size_t)(colbase + r) * 512 + q4 * 8;

    uint4 a0, b0;
    a0 = *(const uint4*)(obbase);
    b0 = *(const uint4*)(Bg);
    *(uint4*)(&As[0][so]) = a0;
    *(uint4*)(&Bs[0][so]) = b0;

    for (int k0 = 0; k0 < 512; k0 += 32) {
        const int cur = (k0 >> 5) & 1;
        __syncthreads();
        if (k0 < 480) {
            const int kn = k0 + 32;
            const ushortT* Ag = obbase + (size_t)(kn >> 6) * 131072 + (kn & 63);
            a0 = *(const uint4*)(Ag);
            b0 = *(const uint4*)(Bg + kn);
        }
        #pragma unroll
        for (int ks = 0; ks < 2; ++ks) {
            const int ko = 16 * ks + 8 * lh;
            short8 af = *(const short8*)(&As[cur][(32 * rh + lm) * 40 + ko]);
            short8 bf = *(const short8*)(&Bs[cur][(32 * ch + lm) * 40 + ko]);
            acc = MFMA32(af, bf, acc);
        }
        if (k0 < 480) {
            const int nxt = cur ^ 1;
            *(uint4*)(&As[nxt][so]) = a0;
            *(uint4*)(&Bs[nxt][so]) = b0;
        }
    }
    const int c = colbase + 32 * ch + lm;
    const float bb = bias[c];
    #pragma unroll
    for (int rg = 0; rg < 16; ++rg) {
        const int row_local = 32 * rh + (rg & 3) + 8 * (rg >> 2) + 4 * lh;
        out[(size_t)(rowbase + row_local) * 512 + c] = acc[rg] + bb;
    }
}

// ---------------------------------------------------------------------------
extern "C" void kernel_launch(void* const* d_in, const int* in_sizes, int n_in,
                              void* d_out, int out_size, void* d_ws, size_t ws_size,
                              hipStream_t stream) {
    const float* x     = (const float*)d_in[0];
    const float* Wqkv  = (const float*)d_in[1];
    const float* bqkv  = (const float*)d_in[2];
    const float* Wproj = (const float*)d_in[3];
    const float* bproj = (const float*)d_in[4];
    float* out = (float*)d_out;

    char* w = (char*)d_ws;
    ushortT* xb     = (ushortT*)(w);                    // 4 MB (dead after qkv -> pc0)
    ushortT* wqkvt  = (ushortT*)(w + 4194304);          // 1.5 MB
    ushortT* wprojt = (ushortT*)(w + 5767168);          // 0.5 MB
    ushortT* qb     = (ushortT*)(w + 6291456);          // 4 MB (scaled 0.125*log2e)
    ushortT* kbuf   = (ushortT*)(w + 10485760);         // 4 MB
    ushortT* vt     = (ushortT*)(w + 14680064);         // 4 MB (transposed per k-block)
    ushortT* ob     = (ushortT*)(w + 18874368);         // 4 MB (final attention output)
    float*   qm     = (float*)(w + 23068672);           // 64 KB
    float*   km     = (float*)(w + 23134208);           // 128 KB
    int*     maskp  = (int*)(w + 23265280);             // 32 KB
    int*     cnt    = (int*)(w + 23298048);             // 1 KB split-K counters
    float*   lp     = (float*)(w + 23299072);           // 512 KB partial l (4 chunks)
    uintT*   pc1    = (uintT*)(w + 23823360);           // 4 MB
    uintT*   pc2    = (uintT*)(w + 28017664);           // 4 MB
    uintT*   pc3    = (uintT*)(w + 32211968);           // 4 MB (end ~36.4 MB)
    uintT*   pc0    = (uintT*)xb;                       // xb dead after qkv

    const int NC = (ws_size >= 36406272 + 4096) ? 4
                 : (ws_size >= 28017664 + 4194304) ? 2 : 1;
    if (NC < 4) { pc2 = pc0; pc3 = pc0; }
    if (NC < 2) { pc1 = pc0; }

    prep_kernel<<<3072, 256, 0, stream>>>(x, xb, Wqkv, wqkvt, Wproj, wprojt, cnt);
    qkv_gemm_kernel<<<dim3(24, 32), 256, 0, stream>>>(xb, wqkvt, bqkv, qb, kbuf, vt, qm, km);
    cosmask_kernel<<<16, 512, 0, stream>>>(qb, kbuf, qm, km, maskp);
    attn_kernel<<<dim3(16, 16, NC), 256, 0, stream>>>(qb, kbuf, vt, maskp,
                                                      pc0, pc1, pc2, pc3, lp, cnt, ob);
    proj_gemm_kernel<<<dim3(8, 64), 256, 0, stream>>>(ob, wprojt, bproj, out);
}

// Round 10
// 165.858 us; speedup vs baseline: 1.7626x; 1.7626x over previous
//
#include <hip/hip_runtime.h>
#include <math.h>

typedef unsigned short ushortT;
typedef unsigned int uintT;
typedef __attribute__((ext_vector_type(8))) short short8;
typedef __attribute__((ext_vector_type(16))) float f32x16;
#define MFMA32(a, b, c) __builtin_amdgcn_mfma_f32_32x32x16_bf16((a), (b), (c), 0, 0, 0)

// MFMA 32x32x16 layouts (gfx950, HW-verified m74/m101/m120):
//  A-frag: lane reads A[m = lane&31][k = (lane>>5)*8 + j], j=0..7
//  B-frag: lane reads B[k = (lane>>5)*8 + j][n = lane&31]
//  C/D:    col = lane&31, row = (reg&3) + 8*(reg>>2) + 4*(lane>>5)

#define LOG2E 1.4426950408889634f

static __device__ __forceinline__ ushortT f2b(float f) {
    union { float f; uintT u; } v; v.f = f;
    uintT u = v.u;
    u += 0x7fffu + ((u >> 16) & 1u);     // round-to-nearest-even
    return (ushortT)(u >> 16);
}
static __device__ __forceinline__ uintT pack2(float a, float b) {
    return (uintT)f2b(a) | ((uintT)f2b(b) << 16);
}
// truncating bf16 pack of two fp32 in ONE v_perm_b32 (low16=a, high16=b)
static __device__ __forceinline__ uintT pack2t(float a, float b) {
    union { float f; uintT u; } x0, x1; x0.f = a; x1.f = b;
    return __builtin_amdgcn_perm(x1.u, x0.u, 0x07060302u);
}
static __device__ __forceinline__ float blo(uintT u) {
    union { uintT u; float f; } v; v.u = u << 16; return v.f;
}
static __device__ __forceinline__ float bhi(uintT u) {
    union { uintT u; float f; } v; v.u = u & 0xffff0000u; return v.f;
}
static __device__ __forceinline__ f32x16 zero16() {
    f32x16 z;
    #pragma unroll
    for (int i = 0; i < 16; ++i) z[i] = 0.f;
    return z;
}

#define B_N 2
#define H_N 8
#define L_N 2048
#define NQB 16
#define NKB 32

// ---------------------------------------------------------------------------
// Fused prep: x fp32->bf16 (blocks 0..2047), Wqkv transpose (2048..2815),
// Wproj transpose (2816..3071).
// ---------------------------------------------------------------------------
__global__ __launch_bounds__(256) void prep_kernel(
    const float* __restrict__ x, ushortT* __restrict__ xb,
    const float* __restrict__ Wq, ushortT* __restrict__ Wqt,
    const float* __restrict__ Wp, ushortT* __restrict__ Wpt) {
    const int bid = blockIdx.x, t = threadIdx.x;
    __shared__ float tile[32][33];
    if (bid < 2048) {
        int i = (bid * 256 + t) * 4;
        float4 v = *(const float4*)(x + i);
        uint2 o; o.x = pack2(v.x, v.y); o.y = pack2(v.z, v.w);
        *(uint2*)(xb + i) = o;
        return;
    }
    const float* W; ushortT* Wt; int C, c0, r0;
    if (bid < 2816) {
        const int b = bid - 2048;
        W = Wq; Wt = Wqt; C = 1536;
        c0 = (b % 48) * 32; r0 = (b / 48) * 32;
    } else {
        const int b = bid - 2816;
        W = Wp; Wt = Wpt; C = 512;
        c0 = (b & 15) * 32; r0 = (b >> 4) * 32;
    }
    const int tx = t & 31, ty = t >> 5;
    #pragma unroll
    for (int i = 0; i < 4; ++i)
        tile[ty + 8 * i][tx] = W[(size_t)(r0 + ty + 8 * i) * C + c0 + tx];
    __syncthreads();
    #pragma unroll
    for (int i = 0; i < 4; ++i) {
        int rr = ty + 8 * i;
        Wt[(size_t)(c0 + rr) * 512 + r0 + tx] = f2b(tile[tx][rr]);
    }
}

// ---------------------------------------------------------------------------
// QKV GEMM (bf16 MFMA): 128x64 tiles, grid (24,32) = 768 blocks = 3/CU.
// Wave w owns rows [32w,32w+32), 2 col-tiles of 32. Double-buffered LDS.
//  -> qb (scaled 0.125*LOG2E), kbuf [bh][L][64], vt [bh][kb][d][64key]
//  fp32 block means qm (scaled 0.125), km.
// ---------------------------------------------------------------------------
__global__ __launch_bounds__(256) void qkv_gemm_kernel(
    const ushortT* __restrict__ xb, const ushortT* __restrict__ wt,
    const float* __restrict__ bias,
    ushortT* __restrict__ qb, ushortT* __restrict__ kbuf, ushortT* __restrict__ vt,
    float* __restrict__ qm, float* __restrict__ km) {
    __shared__ __align__(16) ushortT As[2][128 * 40];
    __shared__ __align__(16) ushortT Bs[2][64 * 40];
    __shared__ float sumbuf[4][64];
    const int t = threadIdx.x;
    const int l = t & 63, w = t >> 6;
    const int lm = l & 31, lh = l >> 5;
    const int rowbase = blockIdx.y * 128;
    const int colbase = blockIdx.x * 64;

    f32x16 acc[2];
    acc[0] = zero16(); acc[1] = zero16();

    // A loader: thread -> row t>>1 (0..127), k-half t&1 (16 elems)
    const int r = t >> 1, half = t & 1;
    const ushortT* Ag = xb + (size_t)(rowbase + r) * 512 + half * 16;
    const int soA = r * 40 + half * 16;
    // B loader: thread -> row t>>2 (0..63), k-quarter t&3 (8 elems)
    const int rb = t >> 2, q4 = t & 3;
    const ushortT* Bg = wt + (size_t)(colbase + rb) * 512 + q4 * 8;
    const int soB = rb * 40 + q4 * 8;

    uint4 a0, a1, b0;
    a0 = *(const uint4*)(Ag); a1 = *(const uint4*)(Ag + 8);
    b0 = *(const uint4*)(Bg);
    *(uint4*)(&As[0][soA]) = a0; *(uint4*)(&As[0][soA] + 8) = a1;
    *(uint4*)(&Bs[0][soB]) = b0;

    for (int k0 = 0; k0 < 512; k0 += 32) {
        const int cur = (k0 >> 5) & 1;
        __syncthreads();
        if (k0 < 480) {
            a0 = *(const uint4*)(Ag + k0 + 32); a1 = *(const uint4*)(Ag + k0 + 40);
            b0 = *(const uint4*)(Bg + k0 + 32);
        }
        #pragma unroll
        for (int ks = 0; ks < 2; ++ks) {
            const int ko = 16 * ks + 8 * lh;
            short8 af  = *(const short8*)(&As[cur][(32 * w + lm) * 40 + ko]);
            short8 b_0 = *(const short8*)(&Bs[cur][lm * 40 + ko]);
            short8 b_1 = *(const short8*)(&Bs[cur][(32 + lm) * 40 + ko]);
            acc[0] = MFMA32(af, b_0, acc[0]);
            acc[1] = MFMA32(af, b_1, acc[1]);
        }
        if (k0 < 480) {
            const int nxt = cur ^ 1;
            *(uint4*)(&As[nxt][soA]) = a0; *(uint4*)(&As[nxt][soA] + 8) = a1;
            *(uint4*)(&Bs[nxt][soB]) = b0;
        }
    }

    // epilogue: 64-col tile = exactly one (which, head)
    const int which = blockIdx.x >> 3;            // 0=q 1=k 2=v
    const int h = blockIdx.x & 7;
    const int by = blockIdx.y;
    const int b = by >> 4;
    const size_t hb = (size_t)(b * 8 + h);
    float bias2[2];
    #pragma unroll
    for (int nt = 0; nt < 2; ++nt) bias2[nt] = bias[colbase + 32 * nt + lm];
    float msum[2] = {0.f, 0.f};
    #pragma unroll
    for (int nt = 0; nt < 2; ++nt) {
        const int dd = 32 * nt + lm;
        #pragma unroll
        for (int rg = 0; rg < 16; ++rg) {
            const int row_local = 32 * w + (rg & 3) + 8 * (rg >> 2) + 4 * lh;
            const int ll = (rowbase + row_local) & 2047;
            float val = acc[nt][rg] + bias2[nt];
            if (which == 0) {
                val *= 0.125f;
                msum[nt] += val;
                qb[(hb * 2048 + ll) * 64 + dd] = f2b(val * LOG2E);
            } else if (which == 1) {
                msum[nt] += val;
                kbuf[(hb * 2048 + ll) * 64 + dd] = f2b(val);
            } else {
                vt[hb * 131072 + (size_t)(ll >> 6) * 4096 + dd * 64 + (ll & 63)] = f2b(val);
            }
        }
    }
    if (which == 2) return;
    #pragma unroll
    for (int nt = 0; nt < 2; ++nt) {
        float s = msum[nt] + __shfl_xor(msum[nt], 32);   // full 32-row col sum
        if (l < 32) sumbuf[w][32 * nt + lm] = s;
    }
    __syncthreads();
    if (which == 0) {
        if (t < 64) {
            const int qbi = by & 15;
            qm[(hb * 16 + qbi) * 64 + t] =
                (sumbuf[0][t] + sumbuf[1][t] + sumbuf[2][t] + sumbuf[3][t]) * (1.0f / 128.0f);
        }
    } else {
        if (t < 128) {
            const int d = t & 63, pair = t >> 6;      // pair 0: waves 0-1, 1: waves 2-3
            const int kbi = 2 * (by & 15) + pair;
            km[(hb * 32 + kbi) * 64 + d] =
                (sumbuf[2 * pair][d] + sumbuf[2 * pair + 1][d]) * (1.0f / 64.0f);
        }
    }
}

// ---------------------------------------------------------------------------
// Fused cos + mask: one block per bh (512 threads). Token min-cosines (qs/ks
// stay in LDS), pooled softmax, sort-free rank-sum CDF keep, fallbacks.
// qb carries a uniform positive scale (0.125*log2e) - cosine scale-invariant.
// ---------------------------------------------------------------------------
__global__ __launch_bounds__(512) void cosmask_kernel(
    const ushortT* __restrict__ qb, const ushortT* __restrict__ kbuf,
    const float* __restrict__ qm, const float* __restrict__ km,
    int* __restrict__ maskp) {
    const int bh = blockIdx.x, t = threadIdx.x;
    __shared__ float qmS[1024];
    __shared__ float kmS[2048];
    __shared__ float nrm[48];        // qn[0..15], kn[16..47]
    __shared__ float pooled[512];
    __shared__ float pnorm[512];
    __shared__ float tokcos[2048];
    __shared__ float qsS[16], ksS[32];
    for (int i = t; i < 1024; i += 512) qmS[i] = qm[(size_t)bh * 1024 + i];
    for (int i = t; i < 2048; i += 512) kmS[i] = km[(size_t)bh * 2048 + i];
    __syncthreads();
    if (t < 16) {
        float s = 0.f;
        #pragma unroll
        for (int d = 0; d < 64; ++d) s += qmS[t * 64 + d] * qmS[t * 64 + d];
        nrm[t] = sqrtf(s);
    } else if (t < 48) {
        const int kb = t - 16;
        float s = 0.f;
        #pragma unroll
        for (int d = 0; d < 64; ++d) s += kmS[kb * 64 + d] * kmS[kb * 64 + d];
        nrm[16 + kb] = sqrtf(s);
    }
    {   // pooled logits (qm pre-scaled by 0.125 -> dot is the scaled logit)
        const int qbi = t >> 5, kbi = t & 31;
        float dot = 0.f;
        #pragma unroll
        for (int d = 0; d < 64; ++d) dot += qmS[qbi * 64 + d] * kmS[kbi * 64 + d];
        pooled[t] = dot;
    }
    __syncthreads();
    // q token cosines: 4 tokens per thread
    for (int tok = t; tok < 2048; tok += 512) {
        const int qbk = tok >> 7;
        const ushortT* row = qb + ((size_t)bh * 2048 + tok) * 64;
        const float* m = &qmS[qbk * 64];
        float dot = 0.f, nn = 0.f;
        #pragma unroll
        for (int c = 0; c < 8; ++c) {
            uint4 u = *(const uint4*)(row + c * 8);
            float f0 = blo(u.x), f1 = bhi(u.x), f2 = blo(u.y), f3 = bhi(u.y);
            float f4 = blo(u.z), f5 = bhi(u.z), f6 = blo(u.w), f7 = bhi(u.w);
            const int db = c * 8;
            dot += f0 * m[db] + f1 * m[db + 1] + f2 * m[db + 2] + f3 * m[db + 3]
                 + f4 * m[db + 4] + f5 * m[db + 5] + f6 * m[db + 6] + f7 * m[db + 7];
            nn += f0 * f0 + f1 * f1 + f2 * f2 + f3 * f3 + f4 * f4 + f5 * f5 + f6 * f6 + f7 * f7;
        }
        tokcos[tok] = dot / ((sqrtf(nn) + 1e-6f) * (nrm[qbk] + 1e-6f));
    }
    __syncthreads();
    if (t < 16) {
        float mn = 1e30f;
        for (int i = 0; i < 128; ++i) mn = fminf(mn, tokcos[t * 128 + i]);
        qsS[t] = mn;
    }
    __syncthreads();   // before tokcos reuse
    // k token cosines
    for (int tok = t; tok < 2048; tok += 512) {
        const int kbk = tok >> 6;
        const ushortT* row = kbuf + ((size_t)bh * 2048 + tok) * 64;
        const float* m = &kmS[kbk * 64];
        float dot = 0.f, nn = 0.f;
        #pragma unroll
        for (int c = 0; c < 8; ++c) {
            uint4 u = *(const uint4*)(row + c * 8);
            float f0 = blo(u.x), f1 = bhi(u.x), f2 = blo(u.y), f3 = bhi(u.y);
            float f4 = blo(u.z), f5 = bhi(u.z), f6 = blo(u.w), f7 = bhi(u.w);
            const int db = c * 8;
            dot += f0 * m[db] + f1 * m[db + 1] + f2 * m[db + 2] + f3 * m[db + 3]
                 + f4 * m[db + 4] + f5 * m[db + 5] + f6 * m[db + 6] + f7 * m[db + 7];
            nn += f0 * f0 + f1 * f1 + f2 * f2 + f3 * f3 + f4 * f4 + f5 * f5 + f6 * f6 + f7 * f7;
        }
        tokcos[tok] = dot / ((sqrtf(nn) + 1e-6f) * (nrm[16 + kbk] + 1e-6f));
    }
    __syncthreads();
    if (t < 32) {
        float mn = 1e30f;
        for (int i = 0; i < 64; ++i) mn = fminf(mn, tokcos[t * 64 + i]);
        ksS[t] = mn;
    } else if (t >= 64 && t < 80) {      // per-row softmax normalize
        const int row = t - 64;
        float mx = -1e30f;
        #pragma unroll
        for (int kb = 0; kb < NKB; ++kb) mx = fmaxf(mx, pooled[row * 32 + kb]);
        float sum = 0.f;
        #pragma unroll
        for (int kb = 0; kb < NKB; ++kb) {
            const float e = expf(pooled[row * 32 + kb] - mx);
            pnorm[row * 32 + kb] = e;
            sum += e;
        }
        const float inv = 1.0f / sum;
        #pragma unroll
        for (int kb = 0; kb < NKB; ++kb) pnorm[row * 32 + kb] *= inv;
    }
    __syncthreads();
    {   // rank-sum CDF keep + fallbacks
        const int row = t >> 5, kb = t & 31;
        const float pk = pnorm[row * 32 + kb];
        float before = 0.f;
        #pragma unroll
        for (int j = 0; j < NKB; ++j) {
            const float pj = pnorm[row * 32 + j];
            if (pj > pk || (pj == pk && j < kb)) before += pj;
        }
        const bool keep = before < 0.98f;
        const bool qfb = !(qsS[row] > 0.6f);
        const bool kfb = !(ksS[kb] > 0.6f);
        maskp[((size_t)bh * 16 + row) * 32 + kb] = (keep || qfb || kfb) ? 1 : 0;
    }
}

// ---------------------------------------------------------------------------
// Flash attention, bf16 MFMA, S^T form, exp2 softmax (scale folded into qb,
// shift cancels in O/l), K-split NC = gridDim.z, LDS double-buffered K/V,
// register P-exchange. Grid (bh, qt, kc): bh on x -> linear-block XCD
// round-robin keeps ~2 heads (1 MB K/V) per XCD L2. Partials to workspace;
// separate reduce kernel (round-9's fused fence/atomic reduction cost 2x -
// cross-XCD fences are catastrophically expensive, G16).
// ---------------------------------------------------------------------------
__global__ __launch_bounds__(256) void attn_kernel(
    const ushortT* __restrict__ qb, const ushortT* __restrict__ kbuf,
    const ushortT* __restrict__ vt, const int* __restrict__ maskp,
    uintT* __restrict__ pc0, uintT* __restrict__ pc1,
    uintT* __restrict__ pc2, uintT* __restrict__ pc3, float* __restrict__ lp) {
    __shared__ __align__(16) ushortT Ks[2][64 * 72];
    __shared__ __align__(16) ushortT Vs[2][64 * 72];
    __shared__ int klist[33];
    const int t = threadIdx.x;
    const int l = t & 63, w = t >> 6;
    const int lm = l & 31, lh = l >> 5;
    const int bh = blockIdx.x, qt = blockIdx.y, kc = blockIdx.z;
    const int NC = gridDim.z;

    // kept-block list via ballot (wave 0)
    if (w == 0) {
        const int* mrow = maskp + ((size_t)bh * 16 + qt) * 32;
        const int keep = (l < 32) ? mrow[l] : 0;
        unsigned long long bal = __ballot(keep != 0);
        if (keep) {
            const int rank = __popcll(bal & ((1ULL << l) - 1ULL));
            klist[rank] = l;
        }
        if (l == 0) klist[32] = __popcll(bal);
    }
    // Q B-frags straight from global
    const ushortT* qg = qb + ((size_t)bh * 2048 + qt * 128) * 64;
    short8 qf[4];
    #pragma unroll
    for (int ksd = 0; ksd < 4; ++ksd)
        qf[ksd] = *(const short8*)(qg + (32 * w + lm) * 64 + 16 * ksd + 8 * lh);
    __syncthreads();   // klist visible

    const int cnt_k = klist[32];
    const int per = cnt_k / NC, rem = cnt_k - per * NC;
    const int n = per + (kc < rem ? 1 : 0);
    const int s = kc * per + (kc < rem ? kc : rem);

    const ushortT* kgb = kbuf + (size_t)bh * 131072;
    const ushortT* vgb = vt + (size_t)bh * 131072;
    const int cr = t >> 3, cp = (t & 7) * 8;
    const int gK0 = cr * 64 + cp, gK1 = gK0 + 2048;
    const int sK0 = cr * 72 + cp, sK1 = sK0 + 2304;

    f32x16 oacc[2];
    oacc[0] = zero16(); oacc[1] = zero16();
    float l_i = 0.f;

    uint4 ka0, ka1, va0, va1;
    if (n > 0) {
        const int kb0 = klist[s];
        const ushortT* kg = kgb + (size_t)kb0 * 4096;
        const ushortT* vg = vgb + (size_t)kb0 * 4096;
        ka0 = *(const uint4*)(kg + gK0); ka1 = *(const uint4*)(kg + gK1);
        va0 = *(const uint4*)(vg + gK0); va1 = *(const uint4*)(vg + gK1);
        *(uint4*)(&Ks[0][sK0]) = ka0; *(uint4*)(&Ks[0][sK1]) = ka1;
        *(uint4*)(&Vs[0][sK0]) = va0; *(uint4*)(&Vs[0][sK1]) = va1;
    }

    for (int i = 0; i < n; ++i) {
        const int cur = i & 1;
        __syncthreads();
        if (i + 1 < n) {
            const int kbn = klist[s + i + 1];
            const ushortT* kg = kgb + (size_t)kbn * 4096;
            const ushortT* vg = vgb + (size_t)kbn * 4096;
            ka0 = *(const uint4*)(kg + gK0); ka1 = *(const uint4*)(kg + gK1);
            va0 = *(const uint4*)(vg + gK0); va1 = *(const uint4*)(vg + gK1);
        }
        // S^T = K * Q^T  (S already in log2e units)
        f32x16 sacc[2];
        sacc[0] = zero16(); sacc[1] = zero16();
        #pragma unroll
        for (int ksd = 0; ksd < 4; ++ksd) {
            const int ko = 16 * ksd + 8 * lh;
            short8 kf0 = *(const short8*)(&Ks[cur][lm * 72 + ko]);
            short8 kf1 = *(const short8*)(&Ks[cur][(32 + lm) * 72 + ko]);
            sacc[0] = MFMA32(kf0, qf[ksd], sacc[0]);
            sacc[1] = MFMA32(kf1, qf[ksd], sacc[1]);
        }
        // p = exp2(s): no shift (global constant cancels in O/l)
        float psum0 = 0.f, psum1 = 0.f;
        uintT uu[2][4][2];   // [mt][rg-block][pair]
        #pragma unroll
        for (int mt = 0; mt < 2; ++mt) {
            #pragma unroll
            for (int rp = 0; rp < 8; ++rp) {
                const float e0 = exp2f(sacc[mt][2 * rp]);
                const float e1 = exp2f(sacc[mt][2 * rp + 1]);
                psum0 += e0; psum1 += e1;
                uu[mt][rp >> 1][rp & 1] = pack2t(e0, e1);
            }
        }
        float psum = psum0 + psum1;
        psum += __shfl_xor(psum, 32);
        l_i += psum;
        // O^T += V^T * P^T ; P^T B-frag via lane pair-exchange
        #pragma unroll
        for (int ksk = 0; ksk < 4; ++ksk) {
            const int mt = ksk >> 1, par = ksk & 1;
            const uintT kA = lh ? uu[mt][2 * par + 1][0] : uu[mt][2 * par][0];
            const uintT kB = lh ? uu[mt][2 * par + 1][1] : uu[mt][2 * par][1];
            const uintT sA = lh ? uu[mt][2 * par][0] : uu[mt][2 * par + 1][0];
            const uintT sB = lh ? uu[mt][2 * par][1] : uu[mt][2 * par + 1][1];
            const uintT rA = (uintT)__shfl_xor((int)sA, 32);
            const uintT rB = (uintT)__shfl_xor((int)sB, 32);
            union { uintT u[4]; short8 v; } cv;
            if (lh == 0) { cv.u[0] = kA; cv.u[1] = kB; cv.u[2] = rA; cv.u[3] = rB; }
            else         { cv.u[0] = rA; cv.u[1] = rB; cv.u[2] = kA; cv.u[3] = kB; }
            const int ko = 16 * ksk + 8 * lh;
            short8 vf0 = *(const short8*)(&Vs[cur][lm * 72 + ko]);
            short8 vf1 = *(const short8*)(&Vs[cur][(32 + lm) * 72 + ko]);
            oacc[0] = MFMA32(vf0, cv.v, oacc[0]);
            oacc[1] = MFMA32(vf1, cv.v, oacc[1]);
        }
        if (i + 1 < n) {
            const int nxt = cur ^ 1;
            *(uint4*)(&Ks[nxt][sK0]) = ka0; *(uint4*)(&Ks[nxt][sK1]) = ka1;
            *(uint4*)(&Vs[nxt][sK0]) = va0; *(uint4*)(&Vs[nxt][sK1]) = va1;
        }
    }
    // epilogue: partial l + partial O^T (bf16, C-layout, coalesced)
    if (lh == 0)
        lp[kc * 32768 + ((size_t)bh * 16 + qt) * 128 + 32 * w + lm] = l_i;
    uintT pu[16];
    #pragma unroll
    for (int mt = 0; mt < 2; ++mt)
        #pragma unroll
        for (int rp = 0; rp < 8; ++rp)
            pu[mt * 8 + rp] = pack2(oacc[mt][2 * rp], oacc[mt][2 * rp + 1]);
    uintT* pcb = (kc == 0) ? pc0 : (kc == 1) ? pc1 : (kc == 2) ? pc2 : pc3;
    uintT* pdst = pcb + (((size_t)bh * 16 + qt) * 4 + w) * 1024 + l * 4;
    #pragma unroll
    for (int i4 = 0; i4 < 4; ++i4)
        *(uint4*)(pdst + i4 * 256) =
            make_uint4(pu[i4 * 4], pu[i4 * 4 + 1], pu[i4 * 4 + 2], pu[i4 * 4 + 3]);
}

// ---------------------------------------------------------------------------
// Reduce: O = (sum_c Oc) / (sum_c lc), C-layout -> [token][d] bf16.
// All partial buffers are dedicated regions (no ob aliasing).
// ---------------------------------------------------------------------------
__global__ __launch_bounds__(256) void reduce_kernel(
    const uintT* __restrict__ pc0, const uintT* __restrict__ pc1,
    const uintT* __restrict__ pc2, const uintT* __restrict__ pc3,
    const float* __restrict__ lp, ushortT* __restrict__ ob, int NC) {
    const int t = threadIdx.x;
    const int l = t & 63, w = t >> 6;
    const int lm = l & 31, lh = l >> 5;
    const int qt = blockIdx.x, bh = blockIdx.y;
    const size_t base = (((size_t)bh * 16 + qt) * 4 + w) * 1024 + l * 4;
    const int qrow = 32 * w + lm;
    float accL[16], accH[16];
    #pragma unroll
    for (int i = 0; i < 16; ++i) { accL[i] = 0.f; accH[i] = 0.f; }
    float lsum = 0.f;
    #pragma unroll
    for (int c = 0; c < 4; ++c) {
        if (c >= NC) break;
        const uintT* p = (c == 0) ? pc0 : (c == 1) ? pc1 : (c == 2) ? pc2 : pc3;
        #pragma unroll
        for (int i4 = 0; i4 < 4; ++i4) {
            uint4 v = *(const uint4*)(p + base + i4 * 256);
            accL[i4 * 4 + 0] += blo(v.x); accH[i4 * 4 + 0] += bhi(v.x);
            accL[i4 * 4 + 1] += blo(v.y); accH[i4 * 4 + 1] += bhi(v.y);
            accL[i4 * 4 + 2] += blo(v.z); accH[i4 * 4 + 2] += bhi(v.z);
            accL[i4 * 4 + 3] += blo(v.w); accH[i4 * 4 + 3] += bhi(v.w);
        }
        lsum += lp[c * 32768 + ((size_t)bh * 16 + qt) * 128 + qrow];
    }
    const float invl = 1.0f / lsum;
    ushortT* orow = ob + ((size_t)bh * 2048 + qt * 128 + qrow) * 64;
    #pragma unroll
    for (int idx = 0; idx < 16; ++idx) {
        const int mt = idx >> 3, rp = idx & 7;
        const int d0 = 32 * mt + 8 * (rp >> 1) + 4 * lh + 2 * (rp & 1);
        *(uintT*)(orow + d0) = pack2(accL[idx] * invl, accH[idx] * invl);
    }
}

// ---------------------------------------------------------------------------
// Proj GEMM: 64x64 tiles, grid (8,64) = 512 blocks = 2 waves/SIMD.
// ob (gathered [4096,512] bf16) @ Wprojt^T + bias -> out fp32.
// ---------------------------------------------------------------------------
__global__ __launch_bounds__(256) void proj_gemm_kernel(
    const ushortT* __restrict__ ob, const ushortT* __restrict__ wpt,
    const float* __restrict__ bias, float* __restrict__ out) {
    __shared__ __align__(16) ushortT As[2][64 * 40];
    __shared__ __align__(16) ushortT Bs[2][64 * 40];
    const int t = threadIdx.x;
    const int l = t & 63, w = t >> 6;
    const int lm = l & 31, lh = l >> 5;
    const int rh = w & 1, ch = w >> 1;            // wave -> 32-row half, 32-col half
    const int rowbase = blockIdx.y * 64;
    const int colbase = blockIdx.x * 64;

    f32x16 acc = zero16();

    const int r = t >> 2, q4 = t & 3;             // row 0..63, k-quarter (8 elems)
    const int token = rowbase + r;
    const int b2 = token >> 11, lt = token & 2047;
    const int so = r * 40 + q4 * 8;
    const ushortT* obbase = ob + ((size_t)(b2 * 8) * 2048 + lt) * 64 + q4 * 8;
    const ushortT* Bg = wpt + (size_t)(colbase + r) * 512 + q4 * 8;

    uint4 a0, b0;
    a0 = *(const uint4*)(obbase);
    b0 = *(const uint4*)(Bg);
    *(uint4*)(&As[0][so]) = a0;
    *(uint4*)(&Bs[0][so]) = b0;

    for (int k0 = 0; k0 < 512; k0 += 32) {
        const int cur = (k0 >> 5) & 1;
        __syncthreads();
        if (k0 < 480) {
            const int kn = k0 + 32;
            const ushortT* Ag = obbase + (size_t)(kn >> 6) * 131072 + (kn & 63);
            a0 = *(const uint4*)(Ag);
            b0 = *(const uint4*)(Bg + kn);
        }
        #pragma unroll
        for (int ks = 0; ks < 2; ++ks) {
            const int ko = 16 * ks + 8 * lh;
            short8 af = *(const short8*)(&As[cur][(32 * rh + lm) * 40 + ko]);
            short8 bf = *(const short8*)(&Bs[cur][(32 * ch + lm) * 40 + ko]);
            acc = MFMA32(af, bf, acc);
        }
        if (k0 < 480) {
            const int nxt = cur ^ 1;
            *(uint4*)(&As[nxt][so]) = a0;
            *(uint4*)(&Bs[nxt][so]) = b0;
        }
    }
    const int c = colbase + 32 * ch + lm;
    const float bb = bias[c];
    #pragma unroll
    for (int rg = 0; rg < 16; ++rg) {
        const int row_local = 32 * rh + (rg & 3) + 8 * (rg >> 2) + 4 * lh;
        out[(size_t)(rowbase + row_local) * 512 + c] = acc[rg] + bb;
    }
}

// ---------------------------------------------------------------------------
extern "C" void kernel_launch(void* const* d_in, const int* in_sizes, int n_in,
                              void* d_out, int out_size, void* d_ws, size_t ws_size,
                              hipStream_t stream) {
    const float* x     = (const float*)d_in[0];
    const float* Wqkv  = (const float*)d_in[1];
    const float* bqkv  = (const float*)d_in[2];
    const float* Wproj = (const float*)d_in[3];
    const float* bproj = (const float*)d_in[4];
    float* out = (float*)d_out;

    char* w = (char*)d_ws;
    ushortT* xb     = (ushortT*)(w);                    // 4 MB (dead after qkv -> pc0)
    ushortT* wqkvt  = (ushortT*)(w + 4194304);          // 1.5 MB
    ushortT* wprojt = (ushortT*)(w + 5767168);          // 0.5 MB
    ushortT* qb     = (ushortT*)(w + 6291456);          // 4 MB (scaled 0.125*log2e)
    ushortT* kbuf   = (ushortT*)(w + 10485760);         // 4 MB
    ushortT* vt     = (ushortT*)(w + 14680064);         // 4 MB (transposed per k-block)
    ushortT* ob     = (ushortT*)(w + 18874368);         // 4 MB (final attention output)
    float*   qm     = (float*)(w + 23068672);           // 64 KB
    float*   km     = (float*)(w + 23134208);           // 128 KB
    int*     maskp  = (int*)(w + 23265280);             // 32 KB
    float*   lp     = (float*)(w + 23299072);           // 512 KB partial l (4 chunks)
    uintT*   pc1    = (uintT*)(w + 23823360);           // 4 MB
    uintT*   pc2    = (uintT*)(w + 28017664);           // 4 MB
    uintT*   pc3    = (uintT*)(w + 32211968);           // 4 MB (end ~36.4 MB)
    uintT*   pc0    = (uintT*)xb;                       // xb dead after qkv

    const int NC = (ws_size >= 36406272 + 4096) ? 4
                 : (ws_size >= 28017664 + 4194304) ? 2 : 1;
    uintT* pc1u = pc1; uintT* pc2u = pc2; uintT* pc3u = pc3;
    if (NC < 4) { pc2u = pc0; pc3u = pc0; }
    if (NC < 2) { pc1u = pc0; }

    prep_kernel<<<3072, 256, 0, stream>>>(x, xb, Wqkv, wqkvt, Wproj, wprojt);
    qkv_gemm_kernel<<<dim3(24, 32), 256, 0, stream>>>(xb, wqkvt, bqkv, qb, kbuf, vt, qm, km);
    cosmask_kernel<<<16, 512, 0, stream>>>(qb, kbuf, qm, km, maskp);
    attn_kernel<<<dim3(16, 16, NC), 256, 0, stream>>>(qb, kbuf, vt, maskp,
                                                      pc0, pc1u, pc2u, pc3u, lp);
    reduce_kernel<<<dim3(16, 16), 256, 0, stream>>>(pc0, pc1u, pc2u, pc3u, lp, ob, NC);
    proj_gemm_kernel<<<dim3(8, 64), 256, 0, stream>>>(ob, wprojt, bproj, out);
}

// Round 11
// 145.711 us; speedup vs baseline: 2.0063x; 1.1383x over previous
//
#include <hip/hip_runtime.h>
#include <math.h>

typedef unsigned short ushortT;
typedef unsigned int uintT;
typedef __attribute__((ext_vector_type(8))) short short8;
typedef __attribute__((ext_vector_type(16))) float f32x16;
#define MFMA32(a, b, c) __builtin_amdgcn_mfma_f32_32x32x16_bf16((a), (b), (c), 0, 0, 0)

// MFMA 32x32x16 layouts (gfx950, HW-verified m74/m101/m120):
//  A-frag: lane reads A[m = lane&31][k = (lane>>5)*8 + j], j=0..7
//  B-frag: lane reads B[k = (lane>>5)*8 + j][n = lane&31]
//  C/D:    col = lane&31, row = (reg&3) + 8*(reg>>2) + 4*(lane>>5)

#define LOG2E 1.4426950408889634f

static __device__ __forceinline__ ushortT f2b(float f) {
    union { float f; uintT u; } v; v.f = f;
    uintT u = v.u;
    u += 0x7fffu + ((u >> 16) & 1u);     // round-to-nearest-even
    return (ushortT)(u >> 16);
}
static __device__ __forceinline__ uintT pack2(float a, float b) {
    return (uintT)f2b(a) | ((uintT)f2b(b) << 16);
}
// truncating bf16 pack of two fp32 in ONE v_perm_b32 (low16=a, high16=b)
static __device__ __forceinline__ uintT pack2t(float a, float b) {
    union { float f; uintT u; } x0, x1; x0.f = a; x1.f = b;
    return __builtin_amdgcn_perm(x1.u, x0.u, 0x07060302u);
}
static __device__ __forceinline__ float blo(uintT u) {
    union { uintT u; float f; } v; v.u = u << 16; return v.f;
}
static __device__ __forceinline__ float bhi(uintT u) {
    union { uintT u; float f; } v; v.u = u & 0xffff0000u; return v.f;
}
static __device__ __forceinline__ f32x16 zero16() {
    f32x16 z;
    #pragma unroll
    for (int i = 0; i < 16; ++i) z[i] = 0.f;
    return z;
}

#define B_N 2
#define H_N 8
#define L_N 2048
#define NQB 16
#define NKB 32

// ---------------------------------------------------------------------------
// Fused prep: x fp32->bf16 (blocks 0..2047), Wqkv transpose (2048..2815),
// Wproj transpose (2816..3071).
// ---------------------------------------------------------------------------
__global__ __launch_bounds__(256) void prep_kernel(
    const float* __restrict__ x, ushortT* __restrict__ xb,
    const float* __restrict__ Wq, ushortT* __restrict__ Wqt,
    const float* __restrict__ Wp, ushortT* __restrict__ Wpt) {
    const int bid = blockIdx.x, t = threadIdx.x;
    __shared__ float tile[32][33];
    if (bid < 2048) {
        int i = (bid * 256 + t) * 4;
        float4 v = *(const float4*)(x + i);
        uint2 o; o.x = pack2(v.x, v.y); o.y = pack2(v.z, v.w);
        *(uint2*)(xb + i) = o;
        return;
    }
    const float* W; ushortT* Wt; int C, c0, r0;
    if (bid < 2816) {
        const int b = bid - 2048;
        W = Wq; Wt = Wqt; C = 1536;
        c0 = (b % 48) * 32; r0 = (b / 48) * 32;
    } else {
        const int b = bid - 2816;
        W = Wp; Wt = Wpt; C = 512;
        c0 = (b & 15) * 32; r0 = (b >> 4) * 32;
    }
    const int tx = t & 31, ty = t >> 5;
    #pragma unroll
    for (int i = 0; i < 4; ++i)
        tile[ty + 8 * i][tx] = W[(size_t)(r0 + ty + 8 * i) * C + c0 + tx];
    __syncthreads();
    #pragma unroll
    for (int i = 0; i < 4; ++i) {
        int rr = ty + 8 * i;
        Wt[(size_t)(c0 + rr) * 512 + r0 + tx] = f2b(tile[tx][rr]);
    }
}

// ---------------------------------------------------------------------------
// QKV GEMM (bf16 MFMA): 128x64 tiles, grid (24,32) = 768 blocks = 3/CU.
// Wave w owns rows [32w,32w+32), 2 col-tiles of 32. Double-buffered LDS.
//  -> qb (scaled 0.125*LOG2E), kbuf [bh][L][64], vt [bh][kb][d][64key]
//  fp32 block means qm (scaled 0.125), km.
// ---------------------------------------------------------------------------
__global__ __launch_bounds__(256) void qkv_gemm_kernel(
    const ushortT* __restrict__ xb, const ushortT* __restrict__ wt,
    const float* __restrict__ bias,
    ushortT* __restrict__ qb, ushortT* __restrict__ kbuf, ushortT* __restrict__ vt,
    float* __restrict__ qm, float* __restrict__ km) {
    __shared__ __align__(16) ushortT As[2][128 * 40];
    __shared__ __align__(16) ushortT Bs[2][64 * 40];
    __shared__ float sumbuf[4][64];
    const int t = threadIdx.x;
    const int l = t & 63, w = t >> 6;
    const int lm = l & 31, lh = l >> 5;
    const int rowbase = blockIdx.y * 128;
    const int colbase = blockIdx.x * 64;

    f32x16 acc[2];
    acc[0] = zero16(); acc[1] = zero16();

    // A loader: thread -> row t>>1 (0..127), k-half t&1 (16 elems)
    const int r = t >> 1, half = t & 1;
    const ushortT* Ag = xb + (size_t)(rowbase + r) * 512 + half * 16;
    const int soA = r * 40 + half * 16;
    // B loader: thread -> row t>>2 (0..63), k-quarter t&3 (8 elems)
    const int rb = t >> 2, q4 = t & 3;
    const ushortT* Bg = wt + (size_t)(colbase + rb) * 512 + q4 * 8;
    const int soB = rb * 40 + q4 * 8;

    uint4 a0, a1, b0;
    a0 = *(const uint4*)(Ag); a1 = *(const uint4*)(Ag + 8);
    b0 = *(const uint4*)(Bg);
    *(uint4*)(&As[0][soA]) = a0; *(uint4*)(&As[0][soA] + 8) = a1;
    *(uint4*)(&Bs[0][soB]) = b0;

    for (int k0 = 0; k0 < 512; k0 += 32) {
        const int cur = (k0 >> 5) & 1;
        __syncthreads();
        if (k0 < 480) {
            a0 = *(const uint4*)(Ag + k0 + 32); a1 = *(const uint4*)(Ag + k0 + 40);
            b0 = *(const uint4*)(Bg + k0 + 32);
        }
        #pragma unroll
        for (int ks = 0; ks < 2; ++ks) {
            const int ko = 16 * ks + 8 * lh;
            short8 af  = *(const short8*)(&As[cur][(32 * w + lm) * 40 + ko]);
            short8 b_0 = *(const short8*)(&Bs[cur][lm * 40 + ko]);
            short8 b_1 = *(const short8*)(&Bs[cur][(32 + lm) * 40 + ko]);
            acc[0] = MFMA32(af, b_0, acc[0]);
            acc[1] = MFMA32(af, b_1, acc[1]);
        }
        if (k0 < 480) {
            const int nxt = cur ^ 1;
            *(uint4*)(&As[nxt][soA]) = a0; *(uint4*)(&As[nxt][soA] + 8) = a1;
            *(uint4*)(&Bs[nxt][soB]) = b0;
        }
    }

    // epilogue: 64-col tile = exactly one (which, head)
    const int which = blockIdx.x >> 3;            // 0=q 1=k 2=v
    const int h = blockIdx.x & 7;
    const int by = blockIdx.y;
    const int b = by >> 4;
    const size_t hb = (size_t)(b * 8 + h);
    float bias2[2];
    #pragma unroll
    for (int nt = 0; nt < 2; ++nt) bias2[nt] = bias[colbase + 32 * nt + lm];
    float msum[2] = {0.f, 0.f};
    #pragma unroll
    for (int nt = 0; nt < 2; ++nt) {
        const int dd = 32 * nt + lm;
        #pragma unroll
        for (int rg = 0; rg < 16; ++rg) {
            const int row_local = 32 * w + (rg & 3) + 8 * (rg >> 2) + 4 * lh;
            const int ll = (rowbase + row_local) & 2047;
            float val = acc[nt][rg] + bias2[nt];
            if (which == 0) {
                val *= 0.125f;
                msum[nt] += val;
                qb[(hb * 2048 + ll) * 64 + dd] = f2b(val * LOG2E);
            } else if (which == 1) {
                msum[nt] += val;
                kbuf[(hb * 2048 + ll) * 64 + dd] = f2b(val);
            } else {
                vt[hb * 131072 + (size_t)(ll >> 6) * 4096 + dd * 64 + (ll & 63)] = f2b(val);
            }
        }
    }
    if (which == 2) return;
    #pragma unroll
    for (int nt = 0; nt < 2; ++nt) {
        float s = msum[nt] + __shfl_xor(msum[nt], 32);   // full 32-row col sum
        if (l < 32) sumbuf[w][32 * nt + lm] = s;
    }
    __syncthreads();
    if (which == 0) {
        if (t < 64) {
            const int qbi = by & 15;
            qm[(hb * 16 + qbi) * 64 + t] =
                (sumbuf[0][t] + sumbuf[1][t] + sumbuf[2][t] + sumbuf[3][t]) * (1.0f / 128.0f);
        }
    } else {
        if (t < 128) {
            const int d = t & 63, pair = t >> 6;      // pair 0: waves 0-1, 1: waves 2-3
            const int kbi = 2 * (by & 15) + pair;
            km[(hb * 32 + kbi) * 64 + d] =
                (sumbuf[2 * pair][d] + sumbuf[2 * pair + 1][d]) * (1.0f / 64.0f);
        }
    }
}

// ---------------------------------------------------------------------------
// Fused min-cosine-to-mean: z=0 -> Q blocks (grid x<16), z=1 -> K blocks.
// WIDE grid (1024 blocks) - round-10's 16-block fused cosmask serialized
// this work on 16 CUs and cost +12us.
// ---------------------------------------------------------------------------
__global__ __launch_bounds__(256) void cos_kernel(const ushortT* __restrict__ qb,
                                                  const ushortT* __restrict__ kbuf,
                                                  const float* __restrict__ qm,
                                                  const float* __restrict__ km,
                                                  float* __restrict__ qs,
                                                  float* __restrict__ ks) {
    const int bh = blockIdx.y, t = threadIdx.x;
    const int l = t & 63, w = t >> 6;
    __shared__ float mS[64];
    __shared__ float wmin[4];
    if (blockIdx.z == 0) {
        if (blockIdx.x >= 16) return;
        const int qbk = blockIdx.x;
        if (t < 64) mS[t] = qm[((size_t)bh * 16 + qbk) * 64 + t];
        __syncthreads();
        float qn = 0.f;
        #pragma unroll
        for (int d = 0; d < 64; ++d) qn += mS[d] * mS[d];
        qn = sqrtf(qn);
        const int tok = t >> 1, half = t & 1;
        const ushortT* qrow = qb + ((size_t)bh * 2048 + qbk * 128 + tok) * 64 + half * 32;
        float dot = 0.f, nn = 0.f;
        #pragma unroll
        for (int c = 0; c < 4; ++c) {
            uint4 u = *(const uint4*)(qrow + c * 8);
            const int db = half * 32 + c * 8;
            float f0 = blo(u.x), f1 = bhi(u.x), f2 = blo(u.y), f3 = bhi(u.y);
            float f4 = blo(u.z), f5 = bhi(u.z), f6 = blo(u.w), f7 = bhi(u.w);
            dot += f0 * mS[db] + f1 * mS[db + 1] + f2 * mS[db + 2] + f3 * mS[db + 3]
                 + f4 * mS[db + 4] + f5 * mS[db + 5] + f6 * mS[db + 6] + f7 * mS[db + 7];
            nn += f0 * f0 + f1 * f1 + f2 * f2 + f3 * f3 + f4 * f4 + f5 * f5 + f6 * f6 + f7 * f7;
        }
        dot += __shfl_xor(dot, 1);
        nn += __shfl_xor(nn, 1);
        float cosv = dot / ((sqrtf(nn) + 1e-6f) * (qn + 1e-6f));
        #pragma unroll
        for (int off = 1; off < 64; off <<= 1) cosv = fminf(cosv, __shfl_xor(cosv, off));
        if (l == 0) wmin[w] = cosv;
        __syncthreads();
        if (t == 0)
            qs[bh * 16 + qbk] = fminf(fminf(wmin[0], wmin[1]), fminf(wmin[2], wmin[3]));
    } else {
        const int kbk = blockIdx.x;
        if (t < 64) mS[t] = km[((size_t)bh * 32 + kbk) * 64 + t];
        __syncthreads();
        float kn = 0.f;
        #pragma unroll
        for (int d = 0; d < 64; ++d) kn += mS[d] * mS[d];
        kn = sqrtf(kn);
        const int tok = t >> 2, quarter = t & 3;
        const ushortT* krow = kbuf + ((size_t)bh * 2048 + kbk * 64 + tok) * 64 + quarter * 16;
        float dot = 0.f, nn = 0.f;
        #pragma unroll
        for (int c = 0; c < 2; ++c) {
            uint4 u = *(const uint4*)(krow + c * 8);
            const int db = quarter * 16 + c * 8;
            float f0 = blo(u.x), f1 = bhi(u.x), f2 = blo(u.y), f3 = bhi(u.y);
            float f4 = blo(u.z), f5 = bhi(u.z), f6 = blo(u.w), f7 = bhi(u.w);
            dot += f0 * mS[db] + f1 * mS[db + 1] + f2 * mS[db + 2] + f3 * mS[db + 3]
                 + f4 * mS[db + 4] + f5 * mS[db + 5] + f6 * mS[db + 6] + f7 * mS[db + 7];
            nn += f0 * f0 + f1 * f1 + f2 * f2 + f3 * f3 + f4 * f4 + f5 * f5 + f6 * f6 + f7 * f7;
        }
        dot += __shfl_xor(dot, 1); dot += __shfl_xor(dot, 2);
        nn += __shfl_xor(nn, 1); nn += __shfl_xor(nn, 2);
        float cosv = dot / ((sqrtf(nn) + 1e-6f) * (kn + 1e-6f));
        #pragma unroll
        for (int off = 1; off < 64; off <<= 1) cosv = fminf(cosv, __shfl_xor(cosv, off));
        if (l == 0) wmin[w] = cosv;
        __syncthreads();
        if (t == 0)
            ks[bh * 32 + kbk] = fminf(fminf(wmin[0], wmin[1]), fminf(wmin[2], wmin[3]));
    }
}

// ---------------------------------------------------------------------------
// Mask: pooled softmax + CDF keep, sort-free rank-sum form. grid 16 (bh).
// ---------------------------------------------------------------------------
__global__ __launch_bounds__(512) void mask_kernel(const float* __restrict__ qm,
                                                   const float* __restrict__ km,
                                                   const float* __restrict__ qs,
                                                   const float* __restrict__ ks,
                                                   int* __restrict__ maskp) {
    const int bh = blockIdx.x, t = threadIdx.x;
    __shared__ float qmS[16 * 64];
    __shared__ float kmS[32 * 64];
    __shared__ float pooled[16 * 32];
    __shared__ float pnorm[16 * 32];
    for (int i = t; i < 1024; i += 512) qmS[i] = qm[(size_t)bh * 1024 + i];
    for (int i = t; i < 2048; i += 512) kmS[i] = km[(size_t)bh * 2048 + i];
    __syncthreads();
    {
        const int qbi = t >> 5, kbi = t & 31;
        float dot = 0.f;
        #pragma unroll
        for (int d = 0; d < 64; ++d) dot += qmS[qbi * 64 + d] * kmS[kbi * 64 + d];
        pooled[t] = dot;
    }
    __syncthreads();
    if (t < 16) {
        float mx = -1e30f;
        #pragma unroll
        for (int kb = 0; kb < NKB; ++kb) mx = fmaxf(mx, pooled[t * 32 + kb]);
        float sum = 0.f;
        #pragma unroll
        for (int kb = 0; kb < NKB; ++kb) {
            const float e = expf(pooled[t * 32 + kb] - mx);
            pnorm[t * 32 + kb] = e;
            sum += e;
        }
        const float inv = 1.0f / sum;
        #pragma unroll
        for (int kb = 0; kb < NKB; ++kb) pnorm[t * 32 + kb] *= inv;
    }
    __syncthreads();
    {
        const int row = t >> 5, kb = t & 31;
        const float pk = pnorm[row * 32 + kb];
        float before = 0.f;
        #pragma unroll
        for (int j = 0; j < NKB; ++j) {
            const float pj = pnorm[row * 32 + j];
            if (pj > pk || (pj == pk && j < kb)) before += pj;
        }
        const bool keep = before < 0.98f;
        const bool qfb = !(qs[bh * 16 + row] > 0.6f);
        const bool kfb = !(ks[bh * 32 + kb] > 0.6f);
        maskp[((size_t)bh * 16 + row) * 32 + kb] = (keep || qfb || kfb) ? 1 : 0;
    }
}

// ---------------------------------------------------------------------------
// Flash attention, bf16 MFMA, S^T form, exp2 softmax (scale folded into qb,
// shift cancels in O/l), K-split NC = gridDim.z, LDS double-buffered K/V,
// register P-exchange. Grid (bh, qt, kc): bh on x -> linear-block XCD
// round-robin keeps ~2 heads (1 MB K/V) per XCD L2 (FETCH 35->6 MB, r10).
// exp via raw v_exp_f32 builtin (domain |s|<~17: no denormal fixup needed).
// ---------------------------------------------------------------------------
__global__ __launch_bounds__(256) void attn_kernel(
    const ushortT* __restrict__ qb, const ushortT* __restrict__ kbuf,
    const ushortT* __restrict__ vt, const int* __restrict__ maskp,
    uintT* __restrict__ pc0, uintT* __restrict__ pc1,
    uintT* __restrict__ pc2, uintT* __restrict__ pc3, float* __restrict__ lp) {
    __shared__ __align__(16) ushortT Ks[2][64 * 72];
    __shared__ __align__(16) ushortT Vs[2][64 * 72];
    __shared__ int klist[33];
    const int t = threadIdx.x;
    const int l = t & 63, w = t >> 6;
    const int lm = l & 31, lh = l >> 5;
    const int bh = blockIdx.x, qt = blockIdx.y, kc = blockIdx.z;
    const int NC = gridDim.z;

    // kept-block list via ballot (wave 0)
    if (w == 0) {
        const int* mrow = maskp + ((size_t)bh * 16 + qt) * 32;
        const int keep = (l < 32) ? mrow[l] : 0;
        unsigned long long bal = __ballot(keep != 0);
        if (keep) {
            const int rank = __popcll(bal & ((1ULL << l) - 1ULL));
            klist[rank] = l;
        }
        if (l == 0) klist[32] = __popcll(bal);
    }
    // Q B-frags straight from global
    const ushortT* qg = qb + ((size_t)bh * 2048 + qt * 128) * 64;
    short8 qf[4];
    #pragma unroll
    for (int ksd = 0; ksd < 4; ++ksd)
        qf[ksd] = *(const short8*)(qg + (32 * w + lm) * 64 + 16 * ksd + 8 * lh);
    __syncthreads();   // klist visible

    const int cnt_k = klist[32];
    const int per = cnt_k / NC, rem = cnt_k - per * NC;
    const int n = per + (kc < rem ? 1 : 0);
    const int s = kc * per + (kc < rem ? kc : rem);

    const ushortT* kgb = kbuf + (size_t)bh * 131072;
    const ushortT* vgb = vt + (size_t)bh * 131072;
    const int cr = t >> 3, cp = (t & 7) * 8;
    const int gK0 = cr * 64 + cp, gK1 = gK0 + 2048;
    const int sK0 = cr * 72 + cp, sK1 = sK0 + 2304;

    f32x16 oacc[2];
    oacc[0] = zero16(); oacc[1] = zero16();
    float l_i = 0.f;

    uint4 ka0, ka1, va0, va1;
    if (n > 0) {
        const int kb0 = klist[s];
        const ushortT* kg = kgb + (size_t)kb0 * 4096;
        const ushortT* vg = vgb + (size_t)kb0 * 4096;
        ka0 = *(const uint4*)(kg + gK0); ka1 = *(const uint4*)(kg + gK1);
        va0 = *(const uint4*)(vg + gK0); va1 = *(const uint4*)(vg + gK1);
        *(uint4*)(&Ks[0][sK0]) = ka0; *(uint4*)(&Ks[0][sK1]) = ka1;
        *(uint4*)(&Vs[0][sK0]) = va0; *(uint4*)(&Vs[0][sK1]) = va1;
    }

    for (int i = 0; i < n; ++i) {
        const int cur = i & 1;
        __syncthreads();
        if (i + 1 < n) {
            const int kbn = klist[s + i + 1];
            const ushortT* kg = kgb + (size_t)kbn * 4096;
            const ushortT* vg = vgb + (size_t)kbn * 4096;
            ka0 = *(const uint4*)(kg + gK0); ka1 = *(const uint4*)(kg + gK1);
            va0 = *(const uint4*)(vg + gK0); va1 = *(const uint4*)(vg + gK1);
        }
        // S^T = K * Q^T  (S already in log2e units)
        f32x16 sacc[2];
        sacc[0] = zero16(); sacc[1] = zero16();
        #pragma unroll
        for (int ksd = 0; ksd < 4; ++ksd) {
            const int ko = 16 * ksd + 8 * lh;
            short8 kf0 = *(const short8*)(&Ks[cur][lm * 72 + ko]);
            short8 kf1 = *(const short8*)(&Ks[cur][(32 + lm) * 72 + ko]);
            sacc[0] = MFMA32(kf0, qf[ksd], sacc[0]);
            sacc[1] = MFMA32(kf1, qf[ksd], sacc[1]);
        }
        // p = exp2(s): raw v_exp_f32 (no shift - global constant cancels)
        float psum0 = 0.f, psum1 = 0.f;
        uintT uu[2][4][2];   // [mt][rg-block][pair]
        #pragma unroll
        for (int mt = 0; mt < 2; ++mt) {
            #pragma unroll
            for (int rp = 0; rp < 8; ++rp) {
                const float e0 = __builtin_amdgcn_exp2f(sacc[mt][2 * rp]);
                const float e1 = __builtin_amdgcn_exp2f(sacc[mt][2 * rp + 1]);
                psum0 += e0; psum1 += e1;
                uu[mt][rp >> 1][rp & 1] = pack2t(e0, e1);
            }
        }
        float psum = psum0 + psum1;
        psum += __shfl_xor(psum, 32);
        l_i += psum;
        // O^T += V^T * P^T ; P^T B-frag via lane pair-exchange
        #pragma unroll
        for (int ksk = 0; ksk < 4; ++ksk) {
            const int mt = ksk >> 1, par = ksk & 1;
            const uintT kA = lh ? uu[mt][2 * par + 1][0] : uu[mt][2 * par][0];
            const uintT kB = lh ? uu[mt][2 * par + 1][1] : uu[mt][2 * par][1];
            const uintT sA = lh ? uu[mt][2 * par][0] : uu[mt][2 * par + 1][0];
            const uintT sB = lh ? uu[mt][2 * par][1] : uu[mt][2 * par + 1][1];
            const uintT rA = (uintT)__shfl_xor((int)sA, 32);
            const uintT rB = (uintT)__shfl_xor((int)sB, 32);
            union { uintT u[4]; short8 v; } cv;
            if (lh == 0) { cv.u[0] = kA; cv.u[1] = kB; cv.u[2] = rA; cv.u[3] = rB; }
            else         { cv.u[0] = rA; cv.u[1] = rB; cv.u[2] = kA; cv.u[3] = kB; }
            const int ko = 16 * ksk + 8 * lh;
            short8 vf0 = *(const short8*)(&Vs[cur][lm * 72 + ko]);
            short8 vf1 = *(const short8*)(&Vs[cur][(32 + lm) * 72 + ko]);
            oacc[0] = MFMA32(vf0, cv.v, oacc[0]);
            oacc[1] = MFMA32(vf1, cv.v, oacc[1]);
        }
        if (i + 1 < n) {
            const int nxt = cur ^ 1;
            *(uint4*)(&Ks[nxt][sK0]) = ka0; *(uint4*)(&Ks[nxt][sK1]) = ka1;
            *(uint4*)(&Vs[nxt][sK0]) = va0; *(uint4*)(&Vs[nxt][sK1]) = va1;
        }
    }
    // epilogue: partial l + partial O^T (bf16, C-layout, coalesced)
    if (lh == 0)
        lp[kc * 32768 + ((size_t)bh * 16 + qt) * 128 + 32 * w + lm] = l_i;
    uintT pu[16];
    #pragma unroll
    for (int mt = 0; mt < 2; ++mt)
        #pragma unroll
        for (int rp = 0; rp < 8; ++rp)
            pu[mt * 8 + rp] = pack2(oacc[mt][2 * rp], oacc[mt][2 * rp + 1]);
    uintT* pcb = (kc == 0) ? pc0 : (kc == 1) ? pc1 : (kc == 2) ? pc2 : pc3;
    uintT* pdst = pcb + (((size_t)bh * 16 + qt) * 4 + w) * 1024 + l * 4;
    #pragma unroll
    for (int i4 = 0; i4 < 4; ++i4)
        *(uint4*)(pdst + i4 * 256) =
            make_uint4(pu[i4 * 4], pu[i4 * 4 + 1], pu[i4 * 4 + 2], pu[i4 * 4 + 3]);
}

// ---------------------------------------------------------------------------
// Reduce: O = (sum_c Oc) / (sum_c lc), C-layout -> [token][d] bf16.
// All partial buffers are dedicated regions (no ob aliasing).
// ---------------------------------------------------------------------------
__global__ __launch_bounds__(256) void reduce_kernel(
    const uintT* __restrict__ pc0, const uintT* __restrict__ pc1,
    const uintT* __restrict__ pc2, const uintT* __restrict__ pc3,
    const float* __restrict__ lp, ushortT* __restrict__ ob, int NC) {
    const int t = threadIdx.x;
    const int l = t & 63, w = t >> 6;
    const int lm = l & 31, lh = l >> 5;
    const int qt = blockIdx.x, bh = blockIdx.y;
    const size_t base = (((size_t)bh * 16 + qt) * 4 + w) * 1024 + l * 4;
    const int qrow = 32 * w + lm;
    float accL[16], accH[16];
    #pragma unroll
    for (int i = 0; i < 16; ++i) { accL[i] = 0.f; accH[i] = 0.f; }
    float lsum = 0.f;
    #pragma unroll
    for (int c = 0; c < 4; ++c) {
        if (c >= NC) break;
        const uintT* p = (c == 0) ? pc0 : (c == 1) ? pc1 : (c == 2) ? pc2 : pc3;
        #pragma unroll
        for (int i4 = 0; i4 < 4; ++i4) {
            uint4 v = *(const uint4*)(p + base + i4 * 256);
            accL[i4 * 4 + 0] += blo(v.x); accH[i4 * 4 + 0] += bhi(v.x);
            accL[i4 * 4 + 1] += blo(v.y); accH[i4 * 4 + 1] += bhi(v.y);
            accL[i4 * 4 + 2] += blo(v.z); accH[i4 * 4 + 2] += bhi(v.z);
            accL[i4 * 4 + 3] += blo(v.w); accH[i4 * 4 + 3] += bhi(v.w);
        }
        lsum += lp[c * 32768 + ((size_t)bh * 16 + qt) * 128 + qrow];
    }
    const float invl = 1.0f / lsum;
    ushortT* orow = ob + ((size_t)bh * 2048 + qt * 128 + qrow) * 64;
    #pragma unroll
    for (int idx = 0; idx < 16; ++idx) {
        const int mt = idx >> 3, rp = idx & 7;
        const int d0 = 32 * mt + 8 * (rp >> 1) + 4 * lh + 2 * (rp & 1);
        *(uintT*)(orow + d0) = pack2(accL[idx] * invl, accH[idx] * invl);
    }
}

// ---------------------------------------------------------------------------
// Proj GEMM: 64x64 tiles, grid (8,64) = 512 blocks = 2 waves/SIMD.
// ob (gathered [4096,512] bf16) @ Wprojt^T + bias -> out fp32.
// ---------------------------------------------------------------------------
__global__ __launch_bounds__(256) void proj_gemm_kernel(
    const ushortT* __restrict__ ob, const ushortT* __restrict__ wpt,
    const float* __restrict__ bias, float* __restrict__ out) {
    __shared__ __align__(16) ushortT As[2][64 * 40];
    __shared__ __align__(16) ushortT Bs[2][64 * 40];
    const int t = threadIdx.x;
    const int l = t & 63, w = t >> 6;
    const int lm = l & 31, lh = l >> 5;
    const int rh = w & 1, ch = w >> 1;            // wave -> 32-row half, 32-col half
    const int rowbase = blockIdx.y * 64;
    const int colbase = blockIdx.x * 64;

    f32x16 acc = zero16();

    const int r = t >> 2, q4 = t & 3;             // row 0..63, k-quarter (8 elems)
    const int token = rowbase + r;
    const int b2 = token >> 11, lt = token & 2047;
    const int so = r * 40 + q4 * 8;
    const ushortT* obbase = ob + ((size_t)(b2 * 8) * 2048 + lt) * 64 + q4 * 8;
    const ushortT* Bg = wpt + (size_t)(colbase + r) * 512 + q4 * 8;

    uint4 a0, b0;
    a0 = *(const uint4*)(obbase);
    b0 = *(const uint4*)(Bg);
    *(uint4*)(&As[0][so]) = a0;
    *(uint4*)(&Bs[0][so]) = b0;

    for (int k0 = 0; k0 < 512; k0 += 32) {
        const int cur = (k0 >> 5) & 1;
        __syncthreads();
        if (k0 < 480) {
            const int kn = k0 + 32;
            const ushortT* Ag = obbase + (size_t)(kn >> 6) * 131072 + (kn & 63);
            a0 = *(const uint4*)(Ag);
            b0 = *(const uint4*)(Bg + kn);
        }
        #pragma unroll
        for (int ks = 0; ks < 2; ++ks) {
            const int ko = 16 * ks + 8 * lh;
            short8 af = *(const short8*)(&As[cur][(32 * rh + lm) * 40 + ko]);
            short8 bf = *(const short8*)(&Bs[cur][(32 * ch + lm) * 40 + ko]);
            acc = MFMA32(af, bf, acc);
        }
        if (k0 < 480) {
            const int nxt = cur ^ 1;
            *(uint4*)(&As[nxt][so]) = a0;
            *(uint4*)(&Bs[nxt][so]) = b0;
        }
    }
    const int c = colbase + 32 * ch + lm;
    const float bb = bias[c];
    #pragma unroll
    for (int rg = 0; rg < 16; ++rg) {
        const int row_local = 32 * rh + (rg & 3) + 8 * (rg >> 2) + 4 * lh;
        out[(size_t)(rowbase + row_local) * 512 + c] = acc[rg] + bb;
    }
}

// ---------------------------------------------------------------------------
extern "C" void kernel_launch(void* const* d_in, const int* in_sizes, int n_in,
                              void* d_out, int out_size, void* d_ws, size_t ws_size,
                              hipStream_t stream) {
    const float* x     = (const float*)d_in[0];
    const float* Wqkv  = (const float*)d_in[1];
    const float* bqkv  = (const float*)d_in[2];
    const float* Wproj = (const float*)d_in[3];
    const float* bproj = (const float*)d_in[4];
    float* out = (float*)d_out;

    char* w = (char*)d_ws;
    ushortT* xb     = (ushortT*)(w);                    // 4 MB (dead after qkv -> pc0)
    ushortT* wqkvt  = (ushortT*)(w + 4194304);          // 1.5 MB
    ushortT* wprojt = (ushortT*)(w + 5767168);          // 0.5 MB
    ushortT* qb     = (ushortT*)(w + 6291456);          // 4 MB (scaled 0.125*log2e)
    ushortT* kbuf   = (ushortT*)(w + 10485760);         // 4 MB
    ushortT* vt     = (ushortT*)(w + 14680064);         // 4 MB (transposed per k-block)
    ushortT* ob     = (ushortT*)(w + 18874368);         // 4 MB (final attention output)
    float*   qm     = (float*)(w + 23068672);           // 64 KB
    float*   km     = (float*)(w + 23134208);           // 128 KB
    int*     maskp  = (int*)(w + 23265280);             // 32 KB
    float*   lp     = (float*)(w + 23299072);           // 512 KB partial l (4 chunks)
    uintT*   pc1    = (uintT*)(w + 23823360);           // 4 MB
    uintT*   pc2    = (uintT*)(w + 28017664);           // 4 MB
    uintT*   pc3    = (uintT*)(w + 32211968);           // 4 MB (end ~36.4 MB)
    float*   qs     = (float*)(w + 36406272);           // 1 KB
    float*   ks     = (float*)(w + 36407296);           // 2 KB
    uintT*   pc0    = (uintT*)xb;                       // xb dead after qkv

    const int NC = (ws_size >= 36409344 + 4096) ? 4
                 : (ws_size >= 28017664 + 4194304) ? 2 : 1;
    uintT* pc1u = pc1; uintT* pc2u = pc2; uintT* pc3u = pc3;
    if (NC < 4) { pc2u = pc0; pc3u = pc0; }
    if (NC < 2) { pc1u = pc0; }

    prep_kernel<<<3072, 256, 0, stream>>>(x, xb, Wqkv, wqkvt, Wproj, wprojt);
    qkv_gemm_kernel<<<dim3(24, 32), 256, 0, stream>>>(xb, wqkvt, bqkv, qb, kbuf, vt, qm, km);
    cos_kernel<<<dim3(32, 16, 2), 256, 0, stream>>>(qb, kbuf, qm, km, qs, ks);
    mask_kernel<<<16, 512, 0, stream>>>(qm, km, qs, ks, maskp);
    attn_kernel<<<dim3(16, 16, NC), 256, 0, stream>>>(qb, kbuf, vt, maskp,
                                                      pc0, pc1u, pc2u, pc3u, lp);
    reduce_kernel<<<dim3(16, 16), 256, 0, stream>>>(pc0, pc1u, pc2u, pc3u, lp, ob, NC);
    proj_gemm_kernel<<<dim3(8, 64), 256, 0, stream>>>(ob, wprojt, bproj, out);
}